// Round 2
// baseline (7515.770 us; speedup 1.0000x reference)
//
#include <hip/hip_runtime.h>
#include <math.h>

#define PX  49      // 7*7
#define CCH 256     // C
#define ECH 1024    // EXP*C
#define NROI 2048
#define HFEAT 12544 // C*49
#define NREG 204
#define NCLS1 51

__device__ __forceinline__ float silu_f(float x) {
    return x / (1.0f + __expf(-x));
}

// ---------------------------------------------------------------------------
// conv_full: out[n][co][x] = epi( sum_k A[co][k]*B[n][k][x] + bias[co] )
// Full M=256 per block (8 co/thread), one ROI per block.
// B_lds layout: slot = py*8+col (col 7 = pad), so each thread (tx = image row)
// reads its 7 pixels as two ds_read_b128.
// EPI 0: silu     EPI 1: BN then silu
// ---------------------------------------------------------------------------
template<int KCH, int EPI>
__global__ __launch_bounds__(256) void conv_full_k(
    const float* __restrict__ A, const float* __restrict__ bias,
    const float* __restrict__ B, float* __restrict__ out, int n0,
    const float* __restrict__ bng, const float* __restrict__ bnb,
    const float* __restrict__ bnm, const float* __restrict__ bnv)
{
    constexpr int KC = 16;
    __shared__ float A_lds[KC][260];   // [k][co], pitch 260 keeps 16B align
    __shared__ float B_lds[KC][64];    // [k][slot], slot = py*8+col
    const int tid = threadIdx.x;
    const int tc = tid >> 3;           // 32 groups: 8 consecutive co each
    const int tx = tid & 7;            // image row (7 = pad row)
    const int nb = blockIdx.y;
    const float* Bn = B + (size_t)nb * KCH * PX;

    float acc[8][7] = {};

    for (int k0 = 0; k0 < KCH; k0 += KC) {
        {   // A tile: each thread stages its own co row's 16 k values
            const float* src = A + (size_t)tid * KCH + k0;
            float4 v0 = *(const float4*)(src);
            float4 v1 = *(const float4*)(src + 4);
            float4 v2 = *(const float4*)(src + 8);
            float4 v3 = *(const float4*)(src + 12);
            A_lds[ 0][tid] = v0.x; A_lds[ 1][tid] = v0.y;
            A_lds[ 2][tid] = v0.z; A_lds[ 3][tid] = v0.w;
            A_lds[ 4][tid] = v1.x; A_lds[ 5][tid] = v1.y;
            A_lds[ 6][tid] = v1.z; A_lds[ 7][tid] = v1.w;
            A_lds[ 8][tid] = v2.x; A_lds[ 9][tid] = v2.y;
            A_lds[10][tid] = v2.z; A_lds[11][tid] = v2.w;
            A_lds[12][tid] = v3.x; A_lds[13][tid] = v3.y;
            A_lds[14][tid] = v3.z; A_lds[15][tid] = v3.w;
        }
        for (int idx = tid; idx < KC * 64; idx += 256) {
            const int kk = idx >> 6, slot = idx & 63;
            const int py = slot >> 3, col = slot & 7;
            float v = 0.f;
            if (py < 7 && col < 7)
                v = Bn[(size_t)(k0 + kk) * PX + py * 7 + col];
            B_lds[kk][slot] = v;
        }
        __syncthreads();
#pragma unroll
        for (int kk = 0; kk < KC; ++kk) {
            float4 a0 = *(const float4*)&A_lds[kk][tc * 8];
            float4 a1 = *(const float4*)&A_lds[kk][tc * 8 + 4];
            float4 b0 = *(const float4*)&B_lds[kk][tx * 8];
            float4 b1 = *(const float4*)&B_lds[kk][tx * 8 + 4];
            const float a[8] = {a0.x, a0.y, a0.z, a0.w, a1.x, a1.y, a1.z, a1.w};
            const float b[7] = {b0.x, b0.y, b0.z, b0.w, b1.x, b1.y, b1.z};
#pragma unroll
            for (int i = 0; i < 8; ++i)
#pragma unroll
                for (int j = 0; j < 7; ++j)
                    acc[i][j] = fmaf(a[i], b[j], acc[i][j]);
        }
        __syncthreads();
    }
    if (tx == 7) return;               // pad row computed zeros; nothing to write
    float* on = out + (size_t)(n0 + nb) * CCH * PX;
#pragma unroll
    for (int i = 0; i < 8; ++i) {
        const int co = tc * 8 + i;
        const float bi = bias[co];
        float sc = 1.f, sh = 0.f;
        if (EPI == 1) {
            const float iv = rsqrtf(bnv[co] + 1e-5f);
            sc = iv * bng[co];
            sh = bnb[co] - bnm[co] * sc;
        }
#pragma unroll
        for (int j = 0; j < 7; ++j) {
            float v = acc[i][j] + bi;
            if (EPI == 1) v = v * sc + sh;
            on[(size_t)co * PX + tx * 7 + j] = silu_f(v);
        }
    }
}

// ---------------------------------------------------------------------------
// FiLM kernel: e-tile 128 (dual scale/shift GEMMs, K=256), one ROI per block.
//   psc[e][x] = Wbpe[e]      . s[n][:,x] + b[e]
//   psh[e][x] = Wbpe[1024+e] . s[n][:,x] + b[1024+e]
//   f[e][x]   = (dw3x3(prev[n][e>>2]) + dw_b[e]) * psc + psh
// Thread: 4 e (all sharing one prev channel since e>>2 is constant) x 7 px.
// ---------------------------------------------------------------------------
__global__ __launch_bounds__(256) void film_k(
    const float* __restrict__ Wbpe, const float* __restrict__ bpe_bias,
    const float* __restrict__ s, const float* __restrict__ prev,
    const float* __restrict__ dw_w, const float* __restrict__ dw_bias,
    float* __restrict__ fbuf, int n0)
{
    constexpr int KC = 16;
    __shared__ float As[KC][132];
    __shared__ float Ah[KC][132];
    __shared__ float B_lds[KC][64];
    const int tid = threadIdx.x;
    const int te = tid >> 3;           // 32 groups: 4 consecutive e each
    const int tx = tid & 7;            // image row (7 = pad)
    const int e0 = blockIdx.x * 128;
    const int nb = blockIdx.y;
    const int n_abs = n0 + nb;
    const float* sn = s + (size_t)n_abs * CCH * PX;

    float accS[4][7] = {}, accH[4][7] = {};

    for (int k0 = 0; k0 < CCH; k0 += KC) {
        {
            const int row = tid >> 1;          // 0..127
            const int kb  = (tid & 1) * 8;
            const float* p0 = Wbpe + (size_t)(e0 + row) * CCH + k0 + kb;
            float4 v0 = *(const float4*)p0;
            float4 v1 = *(const float4*)(p0 + 4);
            As[kb + 0][row] = v0.x; As[kb + 1][row] = v0.y;
            As[kb + 2][row] = v0.z; As[kb + 3][row] = v0.w;
            As[kb + 4][row] = v1.x; As[kb + 5][row] = v1.y;
            As[kb + 6][row] = v1.z; As[kb + 7][row] = v1.w;
            const float* p1 = Wbpe + (size_t)(ECH + e0 + row) * CCH + k0 + kb;
            float4 w0 = *(const float4*)p1;
            float4 w1 = *(const float4*)(p1 + 4);
            Ah[kb + 0][row] = w0.x; Ah[kb + 1][row] = w0.y;
            Ah[kb + 2][row] = w0.z; Ah[kb + 3][row] = w0.w;
            Ah[kb + 4][row] = w1.x; Ah[kb + 5][row] = w1.y;
            Ah[kb + 6][row] = w1.z; Ah[kb + 7][row] = w1.w;
        }
        for (int idx = tid; idx < KC * 64; idx += 256) {
            const int kk = idx >> 6, slot = idx & 63;
            const int py = slot >> 3, col = slot & 7;
            float v = 0.f;
            if (py < 7 && col < 7)
                v = sn[(size_t)(k0 + kk) * PX + py * 7 + col];
            B_lds[kk][slot] = v;
        }
        __syncthreads();
#pragma unroll
        for (int kk = 0; kk < KC; ++kk) {
            float4 aS = *(const float4*)&As[kk][te * 4];
            float4 aH = *(const float4*)&Ah[kk][te * 4];
            float4 b0 = *(const float4*)&B_lds[kk][tx * 8];
            float4 b1 = *(const float4*)&B_lds[kk][tx * 8 + 4];
            const float sv[4] = {aS.x, aS.y, aS.z, aS.w};
            const float hv[4] = {aH.x, aH.y, aH.z, aH.w};
            const float b[7]  = {b0.x, b0.y, b0.z, b0.w, b1.x, b1.y, b1.z};
#pragma unroll
            for (int i = 0; i < 4; ++i)
#pragma unroll
                for (int j = 0; j < 7; ++j) {
                    accS[i][j] = fmaf(sv[i], b[j], accS[i][j]);
                    accH[i][j] = fmaf(hv[i], b[j], accH[i][j]);
                }
        }
        __syncthreads();
    }
    if (tx == 7) return;
    // depthwise: all 4 e of this thread share prev channel (e0+te*4+i)>>2
    const int py = tx;
    const float* pg = prev + ((size_t)n_abs * CCH + (e0 >> 2) + te) * PX;
    float rm[7], rc[7], rp[7];
#pragma unroll
    for (int c = 0; c < 7; ++c) {
        rc[c] = pg[py * 7 + c];
        rm[c] = (py > 0) ? pg[(py - 1) * 7 + c] : 0.f;
        rp[c] = (py < 6) ? pg[(py + 1) * 7 + c] : 0.f;
    }
    float* fo_base = fbuf + (size_t)nb * ECH * PX;
#pragma unroll
    for (int i = 0; i < 4; ++i) {
        const int e = e0 + te * 4 + i;
        const float* wv = dw_w + e * 9;
        const float w0 = wv[0], w1 = wv[1], w2 = wv[2];
        const float w3 = wv[3], w4 = wv[4], w5 = wv[5];
        const float w6 = wv[6], w7 = wv[7], w8 = wv[8];
        const float dwb = dw_bias[e];
        const float bS = bpe_bias[e];
        const float bH = bpe_bias[ECH + e];
        float* fo = fo_base + (size_t)e * PX + py * 7;
#pragma unroll
        for (int j = 0; j < 7; ++j) {
            float sum = dwb;
            if (j > 0) { sum = fmaf(rm[j-1], w0, sum); }
            sum = fmaf(rm[j], w1, sum);
            if (j < 6) { sum = fmaf(rm[j+1], w2, sum); }
            if (j > 0) { sum = fmaf(rc[j-1], w3, sum); }
            sum = fmaf(rc[j], w4, sum);
            if (j < 6) { sum = fmaf(rc[j+1], w5, sum); }
            if (j > 0) { sum = fmaf(rp[j-1], w6, sum); }
            sum = fmaf(rp[j], w7, sum);
            if (j < 6) { sum = fmaf(rp[j+1], w8, sum); }
            fo[j] = fmaf(sum, accS[i][j] + bS, accH[i][j] + bH);
        }
    }
}

// ---------------------------------------------------------------------------
// Head GEMM (NT): y[n][m] = sum_k W[m][k]*feat[n][k] + bias[m]
// M = 255 (204 reg + 51 cls), N = 2048, K = 12544. 64x64 tiles, 4x4/thread.
// ---------------------------------------------------------------------------
__global__ __launch_bounds__(256) void head_k(
    const float* __restrict__ reg_w, const float* __restrict__ reg_b,
    const float* __restrict__ cls_w, const float* __restrict__ cls_b,
    const float* __restrict__ feat, float* __restrict__ out)
{
    constexpr int KC = 32;
    __shared__ float A_lds[KC][68];
    __shared__ float B_lds[KC][68];
    const int tid = threadIdx.x;
    const int tm = tid >> 4, tn = tid & 15;
    const int m0 = blockIdx.x * 64;
    const int nb0 = blockIdx.y * 64;

    float acc[4][4] = {};

    for (int k0 = 0; k0 < HFEAT; k0 += KC) {
        {
            const int row = tid >> 2;
            const int kb  = (tid & 3) * 8;
            const int r = m0 + row;
            float4 v0 = {0,0,0,0}, v1 = {0,0,0,0};
            if (r < NREG) {
                const float* p = reg_w + (size_t)r * HFEAT + k0 + kb;
                v0 = *(const float4*)p; v1 = *(const float4*)(p + 4);
            } else if (r < NREG + NCLS1) {
                const float* p = cls_w + (size_t)(r - NREG) * HFEAT + k0 + kb;
                v0 = *(const float4*)p; v1 = *(const float4*)(p + 4);
            }
            A_lds[kb + 0][row] = v0.x; A_lds[kb + 1][row] = v0.y;
            A_lds[kb + 2][row] = v0.z; A_lds[kb + 3][row] = v0.w;
            A_lds[kb + 4][row] = v1.x; A_lds[kb + 5][row] = v1.y;
            A_lds[kb + 6][row] = v1.z; A_lds[kb + 7][row] = v1.w;
            const float* q = feat + (size_t)(nb0 + row) * HFEAT + k0 + kb;
            float4 u0 = *(const float4*)q;
            float4 u1 = *(const float4*)(q + 4);
            B_lds[kb + 0][row] = u0.x; B_lds[kb + 1][row] = u0.y;
            B_lds[kb + 2][row] = u0.z; B_lds[kb + 3][row] = u0.w;
            B_lds[kb + 4][row] = u1.x; B_lds[kb + 5][row] = u1.y;
            B_lds[kb + 6][row] = u1.z; B_lds[kb + 7][row] = u1.w;
        }
        __syncthreads();
#pragma unroll
        for (int kk = 0; kk < KC; ++kk) {
            float4 a4 = *(const float4*)&A_lds[kk][tm * 4];
            float4 b4 = *(const float4*)&B_lds[kk][tn * 4];
            const float a[4] = {a4.x, a4.y, a4.z, a4.w};
            const float b[4] = {b4.x, b4.y, b4.z, b4.w};
#pragma unroll
            for (int i = 0; i < 4; ++i)
#pragma unroll
                for (int j = 0; j < 4; ++j)
                    acc[i][j] = fmaf(a[i], b[j], acc[i][j]);
        }
        __syncthreads();
    }
#pragma unroll
    for (int i = 0; i < 4; ++i) {
        const int m = m0 + tm * 4 + i;
        if (m >= NREG + NCLS1) continue;
        const float bi = (m < NREG) ? reg_b[m] : cls_b[m - NREG];
#pragma unroll
        for (int j = 0; j < 4; ++j) {
            const int n = nb0 + tn * 4 + j;
            const float v = acc[i][j] + bi;
            if (m < NREG) out[(size_t)n * NREG + m] = v;
            else out[(size_t)NROI * NREG + (size_t)n * NCLS1 + (m - NREG)] = v;
        }
    }
}

// ---------------------------------------------------------------------------
// Softmax over 51 classes, one wave per row
// ---------------------------------------------------------------------------
__global__ __launch_bounds__(256) void softmax_k(float* __restrict__ cls)
{
    const int w = threadIdx.x >> 6, lane = threadIdx.x & 63;
    const int row = blockIdx.x * 4 + w;
    float* p = cls + (size_t)row * NCLS1;
    float v = (lane < NCLS1) ? p[lane] : -INFINITY;
#pragma unroll
    for (int off = 32; off; off >>= 1) v = fmaxf(v, __shfl_xor(v, off));
    const float m = v;
    float e = (lane < NCLS1) ? __expf(p[lane] - m) : 0.f;
    float ssum = e;
#pragma unroll
    for (int off = 32; off; off >>= 1) ssum += __shfl_xor(ssum, off);
    if (lane < NCLS1) p[lane] = e / ssum;
}

// ---------------------------------------------------------------------------
extern "C" void kernel_launch(void* const* d_in, const int* in_sizes, int n_in,
                              void* d_out, int out_size, void* d_ws, size_t ws_size,
                              hipStream_t stream) {
    const float* roi_pool = (const float*)d_in[0];
    const float* roi_pe   = (const float*)d_in[1];
    const float* pe_w     = (const float*)d_in[2];
    const float* pe_b     = (const float*)d_in[3];
    const float* dw_w     = (const float*)d_in[4];
    const float* dw_b     = (const float*)d_in[5];
    const float* bpe_w    = (const float*)d_in[6];
    const float* bpe_b    = (const float*)d_in[7];
    const float* pt_w     = (const float*)d_in[8];
    const float* pt_b     = (const float*)d_in[9];
    const float* bn_g     = (const float*)d_in[10];
    const float* bn_be    = (const float*)d_in[11];
    const float* bn_m     = (const float*)d_in[12];
    const float* bn_v     = (const float*)d_in[13];
    const float* reg_w    = (const float*)d_in[14];
    const float* reg_b    = (const float*)d_in[15];
    const float* cls_w    = (const float*)d_in[16];
    const float* cls_b    = (const float*)d_in[17];
    float* out = (float*)d_out;

    const size_t ACT = (size_t)NROI * CCH * PX;
    float* s_buf = (float*)d_ws;
    float* o_buf = s_buf + ACT;
    float* f_buf = o_buf + ACT;

    const size_t base_bytes = 2 * ACT * sizeof(float);
    int NC = 256;
    while (NC > 8 && base_bytes + (size_t)NC * ECH * PX * sizeof(float) > ws_size)
        NC >>= 1;

    // 1) s = silu(pe_proj(roi_pe))
    conv_full_k<256, 0><<<dim3(1, NROI), 256, 0, stream>>>(
        pe_w, pe_b, roi_pe, s_buf, 0, nullptr, nullptr, nullptr, nullptr);

    // 2) two FiLM blocks
    for (int d = 0; d < 2; ++d) {
        const float* prev = (d == 0) ? roi_pool : o_buf;
        for (int n0 = 0; n0 < NROI; n0 += NC) {
            film_k<<<dim3(8, NC), 256, 0, stream>>>(
                bpe_w + (size_t)d * 2 * ECH * CCH, bpe_b + (size_t)d * 2 * ECH,
                s_buf, prev,
                dw_w + (size_t)d * ECH * 9, dw_b + (size_t)d * ECH,
                f_buf, n0);
            conv_full_k<1024, 1><<<dim3(1, NC), 256, 0, stream>>>(
                pt_w + (size_t)d * CCH * ECH, pt_b + (size_t)d * CCH,
                f_buf, o_buf, n0,
                bn_g + d * CCH, bn_be + d * CCH, bn_m + d * CCH, bn_v + d * CCH);
        }
    }

    // 3) heads + softmax
    head_k<<<dim3(4, NROI / 64), 256, 0, stream>>>(
        reg_w, reg_b, cls_w, cls_b, o_buf, out);
    softmax_k<<<NROI / 4, 256, 0, stream>>>(out + (size_t)NROI * NREG);
}

// Round 4
// 2465.989 us; speedup vs baseline: 3.0478x; 3.0478x over previous
//
#include <hip/hip_runtime.h>
#include <math.h>

#define NROI 2048
#define PXV  49
#define NREG 204
#define NCLS1 51

typedef short v8s __attribute__((ext_vector_type(8)));
typedef float v4f __attribute__((ext_vector_type(4)));

#define PITCH 40   // LDS row pitch in bf16 (80B) -> uniform 2-way banks for b128

__device__ __forceinline__ float silu_f(float x) { return x / (1.0f + __expf(-x)); }

__device__ __forceinline__ short bfc(float x) {           // f32 -> bf16 RNE
    union { float f; unsigned u; } v; v.f = x;
    unsigned r = v.u + 0x7fffu + ((v.u >> 16) & 1u);
    return (short)(r >> 16);
}
__device__ __forceinline__ float b2f(short s) {
    union { unsigned u; float f; } v; v.u = ((unsigned)(unsigned short)s) << 16;
    return v.f;
}

// ---------------------------------------------------------------------------
// Shared MFMA micro-step: 4 waves, wave w owns M rows [w*64,w*64+64) of a
// 256xN64 tile. A_lds [256][PITCH], B_lds [64][PITCH], k-window = 32.
// C/D mapping (HW-verified m89): col = lane&15, row = (lane>>4)*4 + reg.
// A/B k-position maps are symmetric duals -> contiguous-8 staging cancels.
// ---------------------------------------------------------------------------
__device__ __forceinline__ void mma_step(const short* Al, const short* Bl,
                                         int w, int lane, v4f acc[4][4]) {
    const int fr = lane & 15, fg = lane >> 4;
    v8s a[4], b[4];
#pragma unroll
    for (int i = 0; i < 4; ++i)
        a[i] = *(const v8s*)&Al[(w * 64 + i * 16 + fr) * PITCH + fg * 8];
#pragma unroll
    for (int j = 0; j < 4; ++j)
        b[j] = *(const v8s*)&Bl[(j * 16 + fr) * PITCH + fg * 8];
#pragma unroll
    for (int i = 0; i < 4; ++i)
#pragma unroll
        for (int j = 0; j < 4; ++j)
            acc[i][j] = __builtin_amdgcn_mfma_f32_16x16x32_bf16(a[i], b[j], acc[i][j], 0, 0, 0);
}

#define ZERO_ACC(acc) \
    _Pragma("unroll") for (int _i = 0; _i < 4; ++_i) \
    _Pragma("unroll") for (int _j = 0; _j < 4; ++_j) acc[_i][_j] = (v4f){0.f,0.f,0.f,0.f};

// ---------------------------------------------------------------------------
// Weight conversion kernels (re-run every call; ws is re-poisoned)
// ---------------------------------------------------------------------------
__global__ void cvt_k(const float* __restrict__ s, short* __restrict__ d, int n) {
    for (int i = blockIdx.x * 256 + threadIdx.x; i < n; i += gridDim.x * 256)
        d[i] = bfc(s[i]);
}
// bpe weights: row g = t*1024+e  ->  interleaved row 2e+t (scale/shift pairs)
__global__ void cvt_bpe_k(const float* __restrict__ s, short* __restrict__ d) {
    const int N = 2 * 2048 * 256;
    for (int i = blockIdx.x * 256 + threadIdx.x; i < N; i += gridDim.x * 256) {
        int dd = i >> 19, rem = i & ((1 << 19) - 1);
        int g = rem >> 8, k = rem & 255;
        int t = g >> 10, e = g & 1023;
        d[(dd << 19) + ((e * 2 + t) << 8) + k] = bfc(s[i]);
    }
}
// head weights: k' = px*256+ch (matches px-major features); rows >=255 = 0 pad
__global__ void cvt_head_k(const float* __restrict__ rw, const float* __restrict__ cw,
                           short* __restrict__ d) {
    const int N = 256 * 12544;
    for (int i = blockIdx.x * 256 + threadIdx.x; i < N; i += gridDim.x * 256) {
        int m = i / 12544, kk = i - m * 12544;
        int ch = kk / 49, px = kk - ch * 49;
        float v = 0.f;
        if (m < NREG) v = rw[(size_t)m * 12544 + kk];
        else if (m < NREG + NCLS1) v = cw[(size_t)(m - NREG) * 12544 + kk];
        d[(size_t)m * 12544 + px * 256 + ch] = bfc(v);
    }
}

// ---------------------------------------------------------------------------
// pe_k: s_bf[n][px64][256] = silu(pe_w . roi_pe + b), one ROI/block, K=256
// B staged with on-the-fly f32->bf16 transpose (source is ch-major f32).
// ---------------------------------------------------------------------------
__global__ __launch_bounds__(256) void pe_k(const short* __restrict__ Aw,
                                            const float* __restrict__ peb,
                                            const float* __restrict__ roi_pe,
                                            short* __restrict__ s_bf) {
    __shared__ __align__(16) char smem[34048];
    short* Al = (short*)smem;            // [256][40]
    short* Bl = (short*)(smem + 20480);  // [64][40]
    const int tid = threadIdx.x, lane = tid & 63, w = tid >> 6;
    const int n = blockIdx.x;
    const float* Bn = roi_pe + (size_t)n * (256 * 49);
    v4f acc[4][4]; ZERO_ACC(acc);

    for (int k0 = 0; k0 < 256; k0 += 32) {
        int4 av[4];
        { const int4* Ar = (const int4*)(Aw + (size_t)tid * 256 + k0);
#pragma unroll
          for (int c = 0; c < 4; ++c) av[c] = Ar[c]; }
        float4 bv0, bv1;
        const float4* Br = (const float4*)(Bn + k0 * 49);
        bv0 = Br[tid];
        const int has2 = (tid + 256) < 392;
        if (has2) bv1 = Br[tid + 256];
        // prev iteration's mma_step finished at the loop-end barrier
#pragma unroll
        for (int c = 0; c < 4; ++c) *(int4*)&Al[tid * PITCH + c * 8] = av[c];
        {   // scatter-transpose B: flat g -> (ch,px)
            int g = tid * 4;
            const float bb[4] = {bv0.x, bv0.y, bv0.z, bv0.w};
#pragma unroll
            for (int j = 0; j < 4; ++j) {
                int gg = g + j; int ch = gg / 49; int px = gg - ch * 49;
                Bl[px * PITCH + ch] = bfc(bb[j]);
            }
            if (has2) {
                int g2 = (tid + 256) * 4;
                const float bb2[4] = {bv1.x, bv1.y, bv1.z, bv1.w};
#pragma unroll
                for (int j = 0; j < 4; ++j) {
                    int gg = g2 + j; int ch = gg / 49; int px = gg - ch * 49;
                    Bl[px * PITCH + ch] = bfc(bb2[j]);
                }
            }
        }
        __syncthreads();
        mma_step(Al, Bl, w, lane, acc);
        __syncthreads();
    }
    // epilogue: silu -> bounce [64px][264ch] -> coalesced px-major store
    short* ol = (short*)smem;
    const int fr = lane & 15, fg = lane >> 4;
#pragma unroll
    for (int mt = 0; mt < 4; ++mt) {
        const int mb = w * 64 + mt * 16 + fg * 4;
#pragma unroll
        for (int nt = 0; nt < 4; ++nt) {
            const int px = nt * 16 + fr;
#pragma unroll
            for (int r = 0; r < 4; ++r) {
                float v = (px < PXV) ? silu_f(acc[mt][nt][r] + peb[mb + r]) : 0.f;
                ol[px * 264 + mb + r] = bfc(v);
            }
        }
    }
    __syncthreads();
    { int px = tid >> 2, c = tid & 3;
      short* dst = s_bf + ((size_t)n * 64 + px) * 256 + c * 64;
      const short* src = ol + px * 264 + c * 64;
#pragma unroll
      for (int i = 0; i < 8; ++i) ((int4*)dst)[i] = ((const int4*)src)[i]; }
}

// ---------------------------------------------------------------------------
// film_k: per block 1 ROI x 128 e-channels. GEMM rows interleaved (2e+type)
// so each lane's float4 acc = {psc_a, psh_a, psc_b, psh_b}. Depthwise computed
// cooperatively in LDS; f = dwh*psc + psh -> f_bf[nrel][px64][1024] bf16.
// ---------------------------------------------------------------------------
template<int PREVF32>
__global__ __launch_bounds__(256) void film_k(const short* __restrict__ Aw,
                                              const float* __restrict__ bpeb,
                                              const short* __restrict__ s_bf,
                                              const void* __restrict__ prev,
                                              const float* __restrict__ dww,
                                              const float* __restrict__ dwb,
                                              short* __restrict__ f_bf, int n0) {
    __shared__ __align__(16) char smem[56320];
    short* Al = (short*)smem;
    short* Bl = (short*)(smem + 20480);
    const int tid = threadIdx.x, lane = tid & 63, w = tid >> 6;
    const int bx = blockIdx.x;        // 8 tiles of 128 e
    const int nbr = blockIdx.y;
    const int n = n0 + nbr;
    const int e0 = bx * 128;
    const short* Bn = s_bf + (size_t)n * 64 * 256;
    v4f acc[4][4]; ZERO_ACC(acc);

    for (int k0 = 0; k0 < 256; k0 += 32) {
        int4 av[4];
        { const int4* Ar = (const int4*)(Aw + ((size_t)(bx * 256 + tid)) * 256 + k0);
#pragma unroll
          for (int c = 0; c < 4; ++c) av[c] = Ar[c]; }
        int4 bv;
        { int p = tid >> 2, c = tid & 3;
          bv = *(const int4*)(Bn + (size_t)p * 256 + k0 + c * 8); }
#pragma unroll
        for (int c = 0; c < 4; ++c) *(int4*)&Al[tid * PITCH + c * 8] = av[c];
        { int p = tid >> 2, c = tid & 3; *(int4*)&Bl[p * PITCH + c * 8] = bv; }
        __syncthreads();
        mma_step(Al, Bl, w, lane, acc);
        __syncthreads();
    }
    // ---- epilogue ----
    float* prevl = (float*)smem;                       // [32][52]
    float* dwl   = (float*)(smem + 6656);              // [128][10]
    float* dwhl  = (float*)(smem + 6656 + 5120);       // [128][52]
    short* fl    = (short*)(smem + 6656 + 5120 + 26624); // [64][136]
    const int c0 = e0 >> 2;
    if (PREVF32) {
        const float* ps = (const float*)prev + ((size_t)n * 256 + c0) * 49;
        for (int idx = tid; idx < 32 * 49; idx += 256) {
            int ch = idx / 49, px = idx - ch * 49;
            prevl[ch * 52 + px] = ps[idx];
        }
    } else {
        const short* ps = (const short*)prev + ((size_t)n * 256 + c0) * 52;
        for (int idx = tid; idx < 32 * 52; idx += 256) prevl[idx] = b2f(ps[idx]);
    }
    for (int idx = tid; idx < 128 * 9; idx += 256) {
        int e = idx / 9, t9 = idx - e * 9;
        dwl[e * 10 + t9] = dww[(size_t)(e0 + e) * 9 + t9];
    }
    if (tid < 128) dwl[tid * 10 + 9] = dwb[e0 + tid];
    __syncthreads();
    for (int idx = tid; idx < 128 * 49; idx += 256) {
        int e = idx / 49, px = idx - e * 49;
        int py = px / 7, pc = px - py * 7;
        const float* pr = prevl + (e >> 2) * 52;
        const float* ww = dwl + e * 10;
        float sum = ww[9];
        if (py > 0) { const float* r = pr + (py - 1) * 7;
            if (pc > 0) sum = fmaf(r[pc - 1], ww[0], sum);
            sum = fmaf(r[pc], ww[1], sum);
            if (pc < 6) sum = fmaf(r[pc + 1], ww[2], sum); }
        { const float* r = pr + py * 7;
            if (pc > 0) sum = fmaf(r[pc - 1], ww[3], sum);
            sum = fmaf(r[pc], ww[4], sum);
            if (pc < 6) sum = fmaf(r[pc + 1], ww[5], sum); }
        if (py < 6) { const float* r = pr + (py + 1) * 7;
            if (pc > 0) sum = fmaf(r[pc - 1], ww[6], sum);
            sum = fmaf(r[pc], ww[7], sum);
            if (pc < 6) sum = fmaf(r[pc + 1], ww[8], sum); }
        dwhl[e * 52 + px] = sum;
    }
    __syncthreads();
    const int fr = lane & 15, fg = lane >> 4;
#pragma unroll
    for (int mt = 0; mt < 4; ++mt) {
        const int ea = w * 32 + mt * 8 + fg * 2;       // even/odd pair base
        const float bSa = bpeb[e0 + ea],     bHa = bpeb[1024 + e0 + ea];
        const float bSb = bpeb[e0 + ea + 1], bHb = bpeb[1024 + e0 + ea + 1];
#pragma unroll
        for (int nt = 0; nt < 4; ++nt) {
            const int px = nt * 16 + fr;
            unsigned pack = 0;
            if (px < PXV) {
                float fa = dwhl[ea * 52 + px] * (acc[mt][nt][0] + bSa) + (acc[mt][nt][1] + bHa);
                float fb = dwhl[(ea + 1) * 52 + px] * (acc[mt][nt][2] + bSb) + (acc[mt][nt][3] + bHb);
                pack = (unsigned)(unsigned short)bfc(fa) |
                       ((unsigned)(unsigned short)bfc(fb) << 16);
            }
            *(unsigned*)&fl[px * 136 + ea] = pack;
        }
    }
    __syncthreads();
    { int px = tid >> 2, c = tid & 3;
      short* dst = f_bf + ((size_t)nbr * 64 + px) * 1024 + e0 + c * 32;
      const short* src = fl + px * 136 + c * 32;
#pragma unroll
      for (int i = 0; i < 4; ++i) ((int4*)dst)[i] = ((const int4*)src)[i]; }
}

// ---------------------------------------------------------------------------
// pt_k: 1 ROI/block, M=256, K=1024. Epilogue: BN+silu ->
//   PXMAJ=0: o_ch[n][256][52] bf16 (ch-major, for next depthwise)
//   PXMAJ=1: o_bf[n][64][256] bf16 (px-major, head features)
// ---------------------------------------------------------------------------
template<int PXMAJ>
__global__ __launch_bounds__(256) void pt_k(const short* __restrict__ Aw,
                                            const float* __restrict__ ptb,
                                            const short* __restrict__ f_bf,
                                            const float* __restrict__ bng,
                                            const float* __restrict__ bnb,
                                            const float* __restrict__ bnm,
                                            const float* __restrict__ bnv,
                                            short* __restrict__ o_ch,
                                            short* __restrict__ o_bf, int n0) {
    __shared__ __align__(16) char smem[36352];
    short* Al = (short*)smem;
    short* Bl = (short*)(smem + 20480);
    const int tid = threadIdx.x, lane = tid & 63, w = tid >> 6;
    const int nbr = blockIdx.x;
    const int n = n0 + nbr;
    v4f acc[4][4]; ZERO_ACC(acc);

    for (int k0 = 0; k0 < 1024; k0 += 32) {
        int4 av[4];
        { const int4* Ar = (const int4*)(Aw + (size_t)tid * 1024 + k0);
#pragma unroll
          for (int c = 0; c < 4; ++c) av[c] = Ar[c]; }
        int4 bv;
        { int p = tid >> 2, c = tid & 3;
          bv = *(const int4*)(f_bf + ((size_t)nbr * 64 + p) * 1024 + k0 + c * 8); }
#pragma unroll
        for (int c = 0; c < 4; ++c) *(int4*)&Al[tid * PITCH + c * 8] = av[c];
        { int p = tid >> 2, c = tid & 3; *(int4*)&Bl[p * PITCH + c * 8] = bv; }
        __syncthreads();
        mma_step(Al, Bl, w, lane, acc);
        __syncthreads();
    }
    short* ol = (short*)smem;                   // [64][264]
    float* scsh = (float*)(smem + 33792);       // [256][2]
    { float iv = rsqrtf(bnv[tid] + 1e-5f);
      float sc = iv * bng[tid];
      scsh[tid * 2] = sc;
      scsh[tid * 2 + 1] = bnb[tid] - bnm[tid] * sc + ptb[tid] * sc; }
    __syncthreads();
    const int fr = lane & 15, fg = lane >> 4;
#pragma unroll
    for (int mt = 0; mt < 4; ++mt) {
        const int mb = w * 64 + mt * 16 + fg * 4;
#pragma unroll
        for (int nt = 0; nt < 4; ++nt) {
            const int px = nt * 16 + fr;
#pragma unroll
            for (int r = 0; r < 4; ++r) {
                const int m = mb + r;
                float v = (px < PXV) ? silu_f(acc[mt][nt][r] * scsh[m * 2] + scsh[m * 2 + 1]) : 0.f;
                ol[px * 264 + m] = bfc(v);
            }
        }
    }
    __syncthreads();
    if (PXMAJ) {
        int px = tid >> 2, c = tid & 3;
        short* dst = o_bf + ((size_t)n * 64 + px) * 256 + c * 64;
        const short* src = ol + px * 264 + c * 64;
#pragma unroll
        for (int i = 0; i < 8; ++i) ((int4*)dst)[i] = ((const int4*)src)[i];
    } else {
        const int ch = tid;
        short* dst = o_ch + ((size_t)n * 256 + ch) * 52;
#pragma unroll
        for (int i = 0; i < 26; ++i) {
            int p0 = 2 * i, p1 = 2 * i + 1;
            unsigned lo = (p0 < PXV) ? (unsigned)(unsigned short)ol[p0 * 264 + ch] : 0u;
            unsigned hi = (p1 < PXV) ? (unsigned)(unsigned short)ol[p1 * 264 + ch] : 0u;
            *(unsigned*)(dst + p0) = lo | (hi << 16);
        }
    }
}

// ---------------------------------------------------------------------------
// head_k: M=256 (255+pad), N=64 ROIs/block, split-K 14x896 -> partial f32
// ---------------------------------------------------------------------------
__global__ __launch_bounds__(256) void head_k(const short* __restrict__ Aw,
                                              const short* __restrict__ o_bf,
                                              float* __restrict__ part) {
    __shared__ __align__(16) char smem[25600];
    short* Al = (short*)smem;
    short* Bl = (short*)(smem + 20480);
    const int tid = threadIdx.x, lane = tid & 63, w = tid >> 6;
    const int nb0 = blockIdx.x * 64;
    const int ks = blockIdx.y;
    const int kb = ks * 896;
    v4f acc[4][4]; ZERO_ACC(acc);

    for (int k0 = 0; k0 < 896; k0 += 32) {
        int4 av[4];
        { const int4* Ar = (const int4*)(Aw + (size_t)tid * 12544 + kb + k0);
#pragma unroll
          for (int c = 0; c < 4; ++c) av[c] = Ar[c]; }
        int4 bv;
        { int p = tid >> 2, c = tid & 3;
          bv = *(const int4*)(o_bf + (size_t)(nb0 + p) * 16384 + kb + k0 + c * 8); }
#pragma unroll
        for (int c = 0; c < 4; ++c) *(int4*)&Al[tid * PITCH + c * 8] = av[c];
        { int p = tid >> 2, c = tid & 3; *(int4*)&Bl[p * PITCH + c * 8] = bv; }
        __syncthreads();
        mma_step(Al, Bl, w, lane, acc);
        __syncthreads();
    }
    const int fr = lane & 15, fg = lane >> 4;
#pragma unroll
    for (int mt = 0; mt < 4; ++mt) {
        const int mb = w * 64 + mt * 16 + fg * 4;
#pragma unroll
        for (int nt = 0; nt < 4; ++nt) {
            const int nn = nb0 + nt * 16 + fr;
#pragma unroll
            for (int r = 0; r < 4; ++r)
                part[((size_t)ks * NROI + nn) * 256 + mb + r] = acc[mt][nt][r];
        }
    }
}

// ---------------------------------------------------------------------------
// final_k: reduce split-K, add bias, softmax cls. One wave per ROI.
// lane l holds m = l + 64*i
// ---------------------------------------------------------------------------
__global__ __launch_bounds__(256) void final_k(const float* __restrict__ part,
                                               const float* __restrict__ regb,
                                               const float* __restrict__ clsb,
                                               float* __restrict__ out) {
    const int wv = threadIdx.x >> 6, l = threadIdx.x & 63;
    const int n = blockIdx.x * 4 + wv;
    float s[4] = {0.f, 0.f, 0.f, 0.f};
    for (int ks = 0; ks < 14; ++ks) {
        const float* p = part + ((size_t)ks * NROI + n) * 256;
#pragma unroll
        for (int i = 0; i < 4; ++i) s[i] += p[l + 64 * i];
    }
#pragma unroll
    for (int i = 0; i < 4; ++i) {
        int m = l + 64 * i;
        if (m < NREG) out[(size_t)n * NREG + m] = s[i] + regb[m];
    }
    const int m3 = l + 192;
    const bool valid = (m3 >= NREG) && (m3 < NREG + NCLS1);
    float logit = valid ? (s[3] + clsb[m3 - NREG]) : -INFINITY;
    float mx = logit;
#pragma unroll
    for (int off = 32; off; off >>= 1) mx = fmaxf(mx, __shfl_xor(mx, off));
    float e = valid ? __expf(logit - mx) : 0.f;
    float sm = e;
#pragma unroll
    for (int off = 32; off; off >>= 1) sm += __shfl_xor(sm, off);
    if (valid) out[(size_t)NROI * NREG + (size_t)n * NCLS1 + (m3 - NREG)] = e / sm;
}

// ---------------------------------------------------------------------------
extern "C" void kernel_launch(void* const* d_in, const int* in_sizes, int n_in,
                              void* d_out, int out_size, void* d_ws, size_t ws_size,
                              hipStream_t stream) {
    const float* roi_pool = (const float*)d_in[0];
    const float* roi_pe   = (const float*)d_in[1];
    const float* pe_w     = (const float*)d_in[2];
    const float* pe_b     = (const float*)d_in[3];
    const float* dw_w     = (const float*)d_in[4];
    const float* dw_b     = (const float*)d_in[5];
    const float* bpe_w    = (const float*)d_in[6];
    const float* bpe_b    = (const float*)d_in[7];
    const float* pt_w     = (const float*)d_in[8];
    const float* pt_b     = (const float*)d_in[9];
    const float* bn_g     = (const float*)d_in[10];
    const float* bn_be    = (const float*)d_in[11];
    const float* bn_m     = (const float*)d_in[12];
    const float* bn_v     = (const float*)d_in[13];
    const float* reg_w    = (const float*)d_in[14];
    const float* reg_b    = (const float*)d_in[15];
    const float* cls_w    = (const float*)d_in[16];
    const float* cls_b    = (const float*)d_in[17];
    float* out = (float*)d_out;
    char* ws = (char*)d_ws;

    // workspace layout (bytes)
    const size_t S_SZ  = (size_t)NROI * 64 * 256 * 2;          // 67,108,864
    const size_t OC_SZ = (size_t)NROI * 256 * 52 * 2;          // 54,525,952
    short* s_bf  = (short*)ws;
    short* o_bf  = (short*)(ws + S_SZ);
    short* o_ch  = (short*)(ws + 2 * S_SZ);
    char*  wbase = ws + 2 * S_SZ + OC_SZ;
    short* wbpe  = (short*)wbase;                               // 2*2048*256
    short* ptwb  = (short*)(wbase + 2097152);                   // 2*256*1024
    short* pewb  = (short*)(wbase + 2097152 + 1048576);         // 256*256
    short* hwb   = (short*)(wbase + 2097152 + 1048576 + 131072);// 256*12544
    const size_t F_OFF = (size_t)(2 * S_SZ) + OC_SZ + 9699328;
    short* f_bf = (short*)(ws + F_OFF);
    float* part = (float*)ws;   // head partials alias s_bf region (dead by then)

    int NC = 2048;
    while (NC > 32 && F_OFF + (size_t)NC * 131072 > ws_size) NC >>= 1;

    // weights -> bf16 (every call: ws re-poisoned)
    cvt_k<<<64, 256, 0, stream>>>(pe_w, pewb, 256 * 256);
    cvt_k<<<512, 256, 0, stream>>>(pt_w, ptwb, 2 * 256 * 1024);
    cvt_bpe_k<<<1024, 256, 0, stream>>>(bpe_w, wbpe);
    cvt_head_k<<<2048, 256, 0, stream>>>(reg_w, cls_w, hwb);

    // s = silu(pe_proj(roi_pe))  [px-major bf16]
    pe_k<<<NROI, 256, 0, stream>>>(pewb, pe_b, roi_pe, s_bf);

    for (int d = 0; d < 2; ++d) {
        for (int n0 = 0; n0 < NROI; n0 += NC) {
            if (d == 0)
                film_k<1><<<dim3(8, NC), 256, 0, stream>>>(
                    wbpe, bpe_b, s_bf, (const void*)roi_pool,
                    dw_w, dw_b, f_bf, n0);
            else
                film_k<0><<<dim3(8, NC), 256, 0, stream>>>(
                    wbpe + (size_t)2048 * 256, bpe_b + 2048, s_bf, (const void*)o_ch,
                    dw_w + 1024 * 9, dw_b + 1024, f_bf, n0);
            if (d == 0)
                pt_k<0><<<NC, 256, 0, stream>>>(
                    ptwb, pt_b, f_bf, bn_g, bn_be, bn_m, bn_v, o_ch, o_bf, n0);
            else
                pt_k<1><<<NC, 256, 0, stream>>>(
                    ptwb + (size_t)256 * 1024, pt_b + 256, f_bf,
                    bn_g + 256, bn_be + 256, bn_m + 256, bn_v + 256, o_ch, o_bf, n0);
        }
    }

    head_k<<<dim3(32, 14), 256, 0, stream>>>(hwb, o_bf, part);
    final_k<<<NROI / 4, 256, 0, stream>>>(part, reg_b, cls_b, out);
}

// Round 5
// 1374.518 us; speedup vs baseline: 5.4679x; 1.7941x over previous
//
#include <hip/hip_runtime.h>
#include <math.h>

#define NROI 2048
#define PXV  49
#define NREG 204
#define NCLS1 51

typedef short v8s __attribute__((ext_vector_type(8)));
typedef float v4f __attribute__((ext_vector_type(4)));

#define PITCH 40   // LDS row pitch (bf16) for staged A/B tiles in pe/head kernels

__device__ __forceinline__ float silu_f(float x) { return x / (1.0f + __expf(-x)); }

__device__ __forceinline__ short bfc(float x) {           // f32 -> bf16 RNE
    union { float f; unsigned u; } v; v.f = x;
    unsigned r = v.u + 0x7fffu + ((v.u >> 16) & 1u);
    return (short)(r >> 16);
}
__device__ __forceinline__ float b2f(short s) {
    union { unsigned u; float f; } v; v.u = ((unsigned)(unsigned short)s) << 16;
    return v.f;
}

// ---------------------------------------------------------------------------
// LDS-staged MFMA step (pe_k / head_k): 4 waves, wave w owns M rows
// [w*64, w*64+64). C/D map (HW-verified m89): col=lane&15, row=(lane>>4)*4+reg.
// ---------------------------------------------------------------------------
template<int APITCH, int BPITCH>
__device__ __forceinline__ void mma_step(const short* Al, const short* Bl,
                                         int w, int lane, v4f acc[4][4]) {
    const int fr = lane & 15, fg = lane >> 4;
    v8s a[4], b[4];
#pragma unroll
    for (int i = 0; i < 4; ++i)
        a[i] = *(const v8s*)&Al[(w * 64 + i * 16 + fr) * APITCH + fg * 8];
#pragma unroll
    for (int j = 0; j < 4; ++j)
        b[j] = *(const v8s*)&Bl[(j * 16 + fr) * BPITCH + fg * 8];
#pragma unroll
    for (int i = 0; i < 4; ++i)
#pragma unroll
        for (int j = 0; j < 4; ++j)
            acc[i][j] = __builtin_amdgcn_mfma_f32_16x16x32_bf16(a[i], b[j], acc[i][j], 0, 0, 0);
}

// A-in-registers variant (fused kernel): a[] preloaded from global per lane.
template<int BPITCH>
__device__ __forceinline__ void mma_b(const v8s a[4], const short* Bl,
                                      int fr, int fg, v4f acc[4][4]) {
    v8s b[4];
#pragma unroll
    for (int j = 0; j < 4; ++j)
        b[j] = *(const v8s*)&Bl[(j * 16 + fr) * BPITCH + fg * 8];
#pragma unroll
    for (int i = 0; i < 4; ++i)
#pragma unroll
        for (int j = 0; j < 4; ++j)
            acc[i][j] = __builtin_amdgcn_mfma_f32_16x16x32_bf16(a[i], b[j], acc[i][j], 0, 0, 0);
}

#define ZERO_ACC(acc) \
    _Pragma("unroll") for (int _i = 0; _i < 4; ++_i) \
    _Pragma("unroll") for (int _j = 0; _j < 4; ++_j) acc[_i][_j] = (v4f){0.f,0.f,0.f,0.f};

// ---------------------------------------------------------------------------
// Weight conversion kernels (re-run every call; ws is re-poisoned)
// ---------------------------------------------------------------------------
__global__ void cvt_k(const float* __restrict__ s, short* __restrict__ d, int n) {
    for (int i = blockIdx.x * 256 + threadIdx.x; i < n; i += gridDim.x * 256)
        d[i] = bfc(s[i]);
}
// bpe weights: row g = t*1024+e  ->  interleaved row 2e+t (scale/shift pairs)
__global__ void cvt_bpe_k(const float* __restrict__ s, short* __restrict__ d) {
    const int N = 2 * 2048 * 256;
    for (int i = blockIdx.x * 256 + threadIdx.x; i < N; i += gridDim.x * 256) {
        int dd = i >> 19, rem = i & ((1 << 19) - 1);
        int g = rem >> 8, k = rem & 255;
        int t = g >> 10, e = g & 1023;
        d[(dd << 19) + ((e * 2 + t) << 8) + k] = bfc(s[i]);
    }
}
// head weights: k' = px*256+ch (matches px-major features); rows >=255 = 0 pad
__global__ void cvt_head_k(const float* __restrict__ rw, const float* __restrict__ cw,
                           short* __restrict__ d) {
    const int N = 256 * 12544;
    for (int i = blockIdx.x * 256 + threadIdx.x; i < N; i += gridDim.x * 256) {
        int m = i / 12544, kk = i - m * 12544;
        int ch = kk / 49, px = kk - ch * 49;
        float v = 0.f;
        if (m < NREG) v = rw[(size_t)m * 12544 + kk];
        else if (m < NREG + NCLS1) v = cw[(size_t)(m - NREG) * 12544 + kk];
        d[(size_t)m * 12544 + px * 256 + ch] = bfc(v);
    }
}

// ---------------------------------------------------------------------------
// pe_k: s_bf[n][px64][256] = silu(pe_w . roi_pe + b), one ROI/block, K=256
// ---------------------------------------------------------------------------
__global__ __launch_bounds__(256) void pe_k(const short* __restrict__ Aw,
                                            const float* __restrict__ peb,
                                            const float* __restrict__ roi_pe,
                                            short* __restrict__ s_bf) {
    __shared__ __align__(16) char smem[34048];
    short* Al = (short*)smem;            // [256][40]
    short* Bl = (short*)(smem + 20480);  // [64][40]
    const int tid = threadIdx.x, lane = tid & 63, w = tid >> 6;
    const int n = blockIdx.x;
    const float* Bn = roi_pe + (size_t)n * (256 * 49);
    v4f acc[4][4]; ZERO_ACC(acc);

    for (int k0 = 0; k0 < 256; k0 += 32) {
        int4 av[4];
        { const int4* Ar = (const int4*)(Aw + (size_t)tid * 256 + k0);
#pragma unroll
          for (int c = 0; c < 4; ++c) av[c] = Ar[c]; }
        float4 bv0, bv1;
        const float4* Br = (const float4*)(Bn + k0 * 49);
        bv0 = Br[tid];
        const int has2 = (tid + 256) < 392;
        if (has2) bv1 = Br[tid + 256];
#pragma unroll
        for (int c = 0; c < 4; ++c) *(int4*)&Al[tid * PITCH + c * 8] = av[c];
        {   // scatter-transpose B: flat g -> (ch,px)
            int g = tid * 4;
            const float bb[4] = {bv0.x, bv0.y, bv0.z, bv0.w};
#pragma unroll
            for (int j = 0; j < 4; ++j) {
                int gg = g + j; int ch = gg / 49; int px = gg - ch * 49;
                Bl[px * PITCH + ch] = bfc(bb[j]);
            }
            if (has2) {
                int g2 = (tid + 256) * 4;
                const float bb2[4] = {bv1.x, bv1.y, bv1.z, bv1.w};
#pragma unroll
                for (int j = 0; j < 4; ++j) {
                    int gg = g2 + j; int ch = gg / 49; int px = gg - ch * 49;
                    Bl[px * PITCH + ch] = bfc(bb2[j]);
                }
            }
        }
        __syncthreads();
        mma_step<PITCH, PITCH>(Al, Bl, w, lane, acc);
        __syncthreads();
    }
    short* ol = (short*)smem;            // [64][264] bounce
    const int fr = lane & 15, fg = lane >> 4;
#pragma unroll
    for (int mt = 0; mt < 4; ++mt) {
        const int mb = w * 64 + mt * 16 + fg * 4;
#pragma unroll
        for (int nt = 0; nt < 4; ++nt) {
            const int px = nt * 16 + fr;
#pragma unroll
            for (int r = 0; r < 4; ++r) {
                float v = (px < PXV) ? silu_f(acc[mt][nt][r] + peb[mb + r]) : 0.f;
                ol[px * 264 + mb + r] = bfc(v);
            }
        }
    }
    __syncthreads();
    { int px = tid >> 2, c = tid & 3;
      short* dst = s_bf + ((size_t)n * 64 + px) * 256 + c * 64;
      const short* src = ol + px * 264 + c * 64;
#pragma unroll
      for (int i = 0; i < 8; ++i) ((int4*)dst)[i] = ((const int4*)src)[i]; }
}

// ---------------------------------------------------------------------------
// fused_k: one ROI per block. For each of 8 e-tiles (128 e):
//   film GEMM (M=256 interleaved 2e+t, K=256, A from global regs, B=s in LDS)
//   -> depthwise (coop, into f_tile) -> FiLM combine in-place (bf16)
//   -> pt partial accumulation (M=256, K-chunk=128, B=f_tile in LDS)
// K-loops are barrier-free: A prefetched reg-to-reg, B LDS read-only.
// Epilogue: BN+silu -> D0: o_ch [n][256][52]; else: o_bf [n][64][256].
// ---------------------------------------------------------------------------
template<int D0>
__global__ __launch_bounds__(256, 2) void fused_k(
    const short* __restrict__ wbpe,   // [2048][256] rows 2e+t
    const float* __restrict__ bpeb,   // [2048] (1024 scale, 1024 shift)
    const short* __restrict__ ptw,    // [256][1024]
    const float* __restrict__ ptb,
    const short* __restrict__ s_bf,   // [n][64][256]
    const void*  __restrict__ prev,   // D0: f32 [n][256][49]; else bf16 [n][256][52]
    const float* __restrict__ dww, const float* __restrict__ dwb,
    const float* __restrict__ bng, const float* __restrict__ bnb,
    const float* __restrict__ bnm, const float* __restrict__ bnv,
    short* __restrict__ o_ch, short* __restrict__ o_bf)
{
    __shared__ __align__(16) char smem[63616];
    short* s_lds = (short*)smem;               // [64][264]
    short* f_t   = (short*)(smem + 33792);     // [64][136]
    float* prevl = (float*)(smem + 51200);     // [32][53]
    float* dwl   = (float*)(smem + 57984);     // [128][11]
    float* scsh  = (float*)(smem + 51200);     // alias (pt epilogue)

    const int tid = threadIdx.x, lane = tid & 63, w = tid >> 6;
    const int fr = lane & 15, fg = lane >> 4;
    const int n = blockIdx.x;

    // stage s once (B operand for every film GEMM)
    { const int px = tid >> 2, q = tid & 3;
      const int4* src = (const int4*)(s_bf + ((size_t)n * 64 + px) * 256 + q * 64);
      int4* dst = (int4*)(s_lds + px * 264 + q * 64);
#pragma unroll
      for (int i = 0; i < 8; ++i) dst[i] = src[i]; }
    __syncthreads();

    v4f pacc[4][4]; ZERO_ACC(pacc);

    for (int et = 0; et < 8; ++et) {
        // --- epilogue data loads issued up front; latency hides under film ---
        if (D0) {
            const float* ps = (const float*)prev + ((size_t)n * 256 + et * 32) * 49;
            for (int idx = tid; idx < 32 * 49; idx += 256) {
                int ch = idx / 49, px = idx - ch * 49;
                prevl[ch * 53 + px] = ps[idx];
            }
        } else {
            const short* ps = (const short*)prev + ((size_t)n * 256 + et * 32) * 52;
            for (int idx = tid; idx < 32 * 52; idx += 256) {
                int ch = idx / 52, px = idx - ch * 52;
                if (px < PXV) prevl[ch * 53 + px] = b2f(ps[idx]);
            }
        }
        for (int idx = tid; idx < 128 * 9; idx += 256) {
            int e = idx / 9, t9 = idx - e * 9;
            dwl[e * 11 + t9] = dww[(size_t)(et * 128 + e) * 9 + t9];
        }
        if (tid < 128) dwl[tid * 11 + 9] = dwb[et * 128 + tid];

        // --- film GEMM: barrier-free, A prefetched from global ---
        v4f facc[4][4]; ZERO_ACC(facc);
        const short* Af[4];
#pragma unroll
        for (int i = 0; i < 4; ++i)
            Af[i] = wbpe + (size_t)(et * 256 + w * 64 + i * 16 + fr) * 256 + fg * 8;
        v8s a0[4];
#pragma unroll
        for (int i = 0; i < 4; ++i) a0[i] = *(const v8s*)Af[i];
        for (int k0 = 0; k0 < 224; k0 += 32) {
            v8s a1[4];
#pragma unroll
            for (int i = 0; i < 4; ++i) a1[i] = *(const v8s*)(Af[i] + k0 + 32);
            mma_b<264>(a0, s_lds + k0, fr, fg, facc);
#pragma unroll
            for (int i = 0; i < 4; ++i) a0[i] = a1[i];
        }
        mma_b<264>(a0, s_lds + 224, fr, fg, facc);
        __syncthreads();   // prevl/dwl visible; pt(et-1) done with f_t

        // --- cooperative depthwise 3x3 -> f_t (bf16 dwh values) ---
        { const int ch = tid >> 3, py = tid & 7;
          if (py < 7) {
            float rm[7], rc[7], rp[7];
            const float* pr = prevl + ch * 53;
#pragma unroll
            for (int c = 0; c < 7; ++c) {
                rc[c] = pr[py * 7 + c];
                rm[c] = (py > 0) ? pr[(py - 1) * 7 + c] : 0.f;
                rp[c] = (py < 6) ? pr[(py + 1) * 7 + c] : 0.f;
            }
#pragma unroll
            for (int ee = 0; ee < 4; ++ee) {
                const int e = ch * 4 + ee;
                const float* ww = dwl + e * 11;
                const float w0=ww[0],w1=ww[1],w2=ww[2],w3=ww[3],w4=ww[4],
                            w5=ww[5],w6=ww[6],w7=ww[7],w8=ww[8],bb=ww[9];
#pragma unroll
                for (int pc = 0; pc < 7; ++pc) {
                    float sum = bb;
                    if (pc > 0) { sum = fmaf(rm[pc-1], w0, sum);
                                  sum = fmaf(rc[pc-1], w3, sum);
                                  sum = fmaf(rp[pc-1], w6, sum); }
                    sum = fmaf(rm[pc], w1, sum);
                    sum = fmaf(rc[pc], w4, sum);
                    sum = fmaf(rp[pc], w7, sum);
                    if (pc < 6) { sum = fmaf(rm[pc+1], w2, sum);
                                  sum = fmaf(rc[pc+1], w5, sum);
                                  sum = fmaf(rp[pc+1], w8, sum); }
                    f_t[(py * 7 + pc) * 136 + e] = bfc(sum);
                }
            }
          } }
        __syncthreads();

        // --- FiLM combine in place: f = dwh*(psc+bS) + (psh+bH), bf16 pairs ---
#pragma unroll
        for (int mt = 0; mt < 4; ++mt) {
            const int ea = w * 32 + mt * 8 + fg * 2;       // local even e
            const int eg = et * 128 + ea;
            const float bSa = bpeb[eg],     bHa = bpeb[1024 + eg];
            const float bSb = bpeb[eg + 1], bHb = bpeb[1024 + eg + 1];
#pragma unroll
            for (int nt = 0; nt < 4; ++nt) {
                const int px = nt * 16 + fr;
                unsigned* slot = (unsigned*)&f_t[px * 136 + ea];
                unsigned pack = 0;
                if (px < PXV) {
                    const unsigned din = *slot;
                    const float da = b2f((short)(din & 0xffff));
                    const float db = b2f((short)(din >> 16));
                    float fa = da * (facc[mt][nt][0] + bSa) + (facc[mt][nt][1] + bHa);
                    float fb = db * (facc[mt][nt][2] + bSb) + (facc[mt][nt][3] + bHb);
                    pack = (unsigned)(unsigned short)bfc(fa) |
                           ((unsigned)(unsigned short)bfc(fb) << 16);
                }
                *slot = pack;
            }
        }
        __syncthreads();

        // --- pt partial accumulation over this 128-e chunk, barrier-free ---
        const short* Ap[4];
#pragma unroll
        for (int i = 0; i < 4; ++i)
            Ap[i] = ptw + (size_t)(w * 64 + i * 16 + fr) * 1024 + et * 128 + fg * 8;
        v8s p0[4];
#pragma unroll
        for (int i = 0; i < 4; ++i) p0[i] = *(const v8s*)Ap[i];
        for (int kk = 0; kk < 96; kk += 32) {
            v8s p1[4];
#pragma unroll
            for (int i = 0; i < 4; ++i) p1[i] = *(const v8s*)(Ap[i] + kk + 32);
            mma_b<136>(p0, f_t + kk, fr, fg, pacc);
#pragma unroll
            for (int i = 0; i < 4; ++i) p0[i] = p1[i];
        }
        mma_b<136>(p0, f_t + 96, fr, fg, pacc);
        __syncthreads();   // all waves done with f_t before next et's dwh
    }

    // --- pt epilogue: BN + silu ---
    { const float iv = rsqrtf(bnv[tid] + 1e-5f);
      const float sc = iv * bng[tid];
      scsh[tid * 2] = sc;
      scsh[tid * 2 + 1] = bnb[tid] - bnm[tid] * sc + ptb[tid] * sc; }
    __syncthreads();
    short* ol = s_lds;    // [64][264] bounce (s dead)
#pragma unroll
    for (int mt = 0; mt < 4; ++mt) {
        const int mb = w * 64 + mt * 16 + fg * 4;
#pragma unroll
        for (int nt = 0; nt < 4; ++nt) {
            const int px = nt * 16 + fr;
#pragma unroll
            for (int r = 0; r < 4; ++r) {
                const int m = mb + r;
                float v = (px < PXV) ? silu_f(pacc[mt][nt][r] * scsh[m*2] + scsh[m*2+1]) : 0.f;
                ol[px * 264 + m] = bfc(v);
            }
        }
    }
    __syncthreads();
    if (D0) {
        const int ch = tid;
        short* dst = o_ch + ((size_t)n * 256 + ch) * 52;
#pragma unroll
        for (int i = 0; i < 26; ++i) {
            const int pp0 = 2 * i, pp1 = 2 * i + 1;
            unsigned lo = (unsigned)(unsigned short)ol[pp0 * 264 + ch];
            unsigned hi = (unsigned)(unsigned short)ol[pp1 * 264 + ch];
            *(unsigned*)(dst + pp0) = lo | (hi << 16);
        }
    } else {
        const int px = tid >> 2, q = tid & 3;
        int4* dst = (int4*)(o_bf + ((size_t)n * 64 + px) * 256 + q * 64);
        const int4* src = (const int4*)(ol + px * 264 + q * 64);
#pragma unroll
        for (int i = 0; i < 8; ++i) dst[i] = src[i];
    }
}

// ---------------------------------------------------------------------------
// head_k: M=256 (255+pad), N=64 ROIs/block, split-K 14x896 -> partial f32
// ---------------------------------------------------------------------------
__global__ __launch_bounds__(256) void head_k(const short* __restrict__ Aw,
                                              const short* __restrict__ o_bf,
                                              float* __restrict__ part) {
    __shared__ __align__(16) char smem[25600];
    short* Al = (short*)smem;
    short* Bl = (short*)(smem + 20480);
    const int tid = threadIdx.x, lane = tid & 63, w = tid >> 6;
    const int nb0 = blockIdx.x * 64;
    const int ks = blockIdx.y;
    const int kb = ks * 896;
    v4f acc[4][4]; ZERO_ACC(acc);

    for (int k0 = 0; k0 < 896; k0 += 32) {
        int4 av[4];
        { const int4* Ar = (const int4*)(Aw + (size_t)tid * 12544 + kb + k0);
#pragma unroll
          for (int c = 0; c < 4; ++c) av[c] = Ar[c]; }
        int4 bv;
        { int p = tid >> 2, c = tid & 3;
          bv = *(const int4*)(o_bf + (size_t)(nb0 + p) * 16384 + kb + k0 + c * 8); }
#pragma unroll
        for (int c = 0; c < 4; ++c) *(int4*)&Al[tid * PITCH + c * 8] = av[c];
        { int p = tid >> 2, c = tid & 3; *(int4*)&Bl[p * PITCH + c * 8] = bv; }
        __syncthreads();
        mma_step<PITCH, PITCH>(Al, Bl, w, lane, acc);
        __syncthreads();
    }
    const int fr = lane & 15, fg = lane >> 4;
#pragma unroll
    for (int mt = 0; mt < 4; ++mt) {
        const int mb = w * 64 + mt * 16 + fg * 4;
#pragma unroll
        for (int nt = 0; nt < 4; ++nt) {
            const int nn = nb0 + nt * 16 + fr;
#pragma unroll
            for (int r = 0; r < 4; ++r)
                part[((size_t)ks * NROI + nn) * 256 + mb + r] = acc[mt][nt][r];
        }
    }
}

// ---------------------------------------------------------------------------
// final_k: reduce split-K, add bias, softmax cls. One wave per ROI.
// ---------------------------------------------------------------------------
__global__ __launch_bounds__(256) void final_k(const float* __restrict__ part,
                                               const float* __restrict__ regb,
                                               const float* __restrict__ clsb,
                                               float* __restrict__ out) {
    const int wv = threadIdx.x >> 6, l = threadIdx.x & 63;
    const int n = blockIdx.x * 4 + wv;
    float s[4] = {0.f, 0.f, 0.f, 0.f};
    for (int ks = 0; ks < 14; ++ks) {
        const float* p = part + ((size_t)ks * NROI + n) * 256;
#pragma unroll
        for (int i = 0; i < 4; ++i) s[i] += p[l + 64 * i];
    }
#pragma unroll
    for (int i = 0; i < 4; ++i) {
        int m = l + 64 * i;
        if (m < NREG) out[(size_t)n * NREG + m] = s[i] + regb[m];
    }
    const int m3 = l + 192;
    const bool valid = (m3 >= NREG) && (m3 < NREG + NCLS1);
    float logit = valid ? (s[3] + clsb[m3 - NREG]) : -INFINITY;
    float mx = logit;
#pragma unroll
    for (int off = 32; off; off >>= 1) mx = fmaxf(mx, __shfl_xor(mx, off));
    float e = valid ? __expf(logit - mx) : 0.f;
    float sm = e;
#pragma unroll
    for (int off = 32; off; off >>= 1) sm += __shfl_xor(sm, off);
    if (valid) out[(size_t)NROI * NREG + (size_t)n * NCLS1 + (m3 - NREG)] = e / sm;
}

// ---------------------------------------------------------------------------
extern "C" void kernel_launch(void* const* d_in, const int* in_sizes, int n_in,
                              void* d_out, int out_size, void* d_ws, size_t ws_size,
                              hipStream_t stream) {
    const float* roi_pool = (const float*)d_in[0];
    const float* roi_pe   = (const float*)d_in[1];
    const float* pe_w     = (const float*)d_in[2];
    const float* pe_b     = (const float*)d_in[3];
    const float* dw_w     = (const float*)d_in[4];
    const float* dw_b     = (const float*)d_in[5];
    const float* bpe_w    = (const float*)d_in[6];
    const float* bpe_b    = (const float*)d_in[7];
    const float* pt_w     = (const float*)d_in[8];
    const float* pt_b     = (const float*)d_in[9];
    const float* bn_g     = (const float*)d_in[10];
    const float* bn_be    = (const float*)d_in[11];
    const float* bn_m     = (const float*)d_in[12];
    const float* bn_v     = (const float*)d_in[13];
    const float* reg_w    = (const float*)d_in[14];
    const float* reg_b    = (const float*)d_in[15];
    const float* cls_w    = (const float*)d_in[16];
    const float* cls_b    = (const float*)d_in[17];
    float* out = (float*)d_out;
    char* ws = (char*)d_ws;

    // workspace layout (bytes)
    const size_t S_SZ  = (size_t)NROI * 64 * 256 * 2;          // 67,108,864
    const size_t OC_SZ = (size_t)NROI * 256 * 52 * 2;          // 54,525,952
    short* s_bf  = (short*)ws;
    short* o_bf  = (short*)(ws + S_SZ);
    short* o_ch  = (short*)(ws + 2 * S_SZ);
    char*  wbase = ws + 2 * S_SZ + OC_SZ;
    short* wbpe  = (short*)wbase;                               // 2*2048*256
    short* ptwb  = (short*)(wbase + 2097152);                   // 2*256*1024
    short* pewb  = (short*)(wbase + 2097152 + 1048576);         // 256*256
    short* hwb   = (short*)(wbase + 2097152 + 1048576 + 131072);// 256*12544
    float* part  = (float*)ws;   // head partials alias s_bf (dead by then)

    // weights -> bf16 (every call: ws re-poisoned)
    cvt_k<<<64, 256, 0, stream>>>(pe_w, pewb, 256 * 256);
    cvt_k<<<512, 256, 0, stream>>>(pt_w, ptwb, 2 * 256 * 1024);
    cvt_bpe_k<<<1024, 256, 0, stream>>>(bpe_w, wbpe);
    cvt_head_k<<<2048, 256, 0, stream>>>(reg_w, cls_w, hwb);

    // s = silu(pe_proj(roi_pe))  [px-major bf16]
    pe_k<<<NROI, 256, 0, stream>>>(pewb, pe_b, roi_pe, s_bf);

    // layer 0: prev = roi_pool (f32), out -> o_ch (ch-major)
    fused_k<1><<<NROI, 256, 0, stream>>>(
        wbpe, bpe_b, ptwb, pt_b, s_bf, (const void*)roi_pool,
        dw_w, dw_b, bn_g, bn_be, bn_m, bn_v, o_ch, o_bf);
    // layer 1: prev = o_ch (bf16), out -> o_bf (px-major head features)
    fused_k<0><<<NROI, 256, 0, stream>>>(
        wbpe + (size_t)2048 * 256, bpe_b + 2048,
        ptwb + (size_t)256 * 1024, pt_b + 256, s_bf, (const void*)o_ch,
        dw_w + 1024 * 9, dw_b + 1024,
        bn_g + 256, bn_be + 256, bn_m + 256, bn_v + 256, o_ch, o_bf);

    head_k<<<dim3(32, 14), 256, 0, stream>>>(hwb, o_bf, part);
    final_k<<<NROI / 4, 256, 0, stream>>>(part, reg_b, cls_b, out);
}